// Round 6
// baseline (290.509 us; speedup 1.0000x reference)
//
#include <hip/hip_runtime.h>
#include <math.h>

typedef _Float16 f16;
typedef _Float16 f16x8 __attribute__((ext_vector_type(8)));
typedef float f32x4 __attribute__((ext_vector_type(4)));

#define H2_STRIDE 140   // f16 per LDS row: 280 B = 70 dw; 70 mod 32 = 6.
                        // phaseA b16 writes: quad dword offsets {0,24,16,8} -> conflict-free
                        //   (validated: r4/r5 measured SQ_LDS_BANK_CONFLICT = 0).
                        // phaseB b128 reads: exactly 8 dw/bank -> minimum cycles.

// ---------------------------------------------------------------------------
// Fused PointNet: layers 1-3 + max-pool, one block per batch (grid = 256 =
// 1 block/CU).  512 threads = 8 waves.
// REGISTER DISCIPLINE (r2+r4): bf3 = 128 VGPRs resident =>
//  (a) __launch_bounds__(512, 2) required (256-reg budget; min-waves=4 forced
//      128 regs -> full spill, 8.7x slowdown).
//  (b) schedule must not extend live ranges (r4's 2-chunk window -> ~90 regs
//      spilled, 47 MB scratch).  Keep 1 barrier per chunk.
// SCHEDULING (r5): NO s_setprio around phaseB — measured −23 µs regression
//  (MfmaUtil 41.5->31.9, VALUBusy 32->24: B-wave priority starved A-waves'
//  VALU issue, serializing the cross-wave A/B pipe overlap; matches m190).
// Weights loaded DIRECTLY from fp32 W1/W2/W3 (r0-proven pattern, L2-resident,
// 16-lane-contiguous) — removes the prep kernel + its launch gap.
// ---------------------------------------------------------------------------
__global__ __launch_bounds__(512, 2) void pointnet_fused(
    const float* __restrict__ x,   // [B][1024][3]
    const float* __restrict__ W1,  // [3][64]
    const float* __restrict__ b1,  // [64]
    const float* __restrict__ W2,  // [64][128]
    const float* __restrict__ b2,  // [128]
    const float* __restrict__ W3,  // [128][1024]
    const float* __restrict__ b3,  // [1024]
    float* __restrict__ g)         // [B][1024]
{
    __shared__ float xs[1024 * 3];                        // 12 KB, whole batch
    __shared__ __align__(16) float wls[288];              // staggered W1+b1 pack
    __shared__ float b2s[128];
    __shared__ __align__(16) f16 h2s[2][128 * H2_STRIDE]; // 2 x 35 KB

    int b = blockIdx.x;
    int tid = threadIdx.x;
    int lane = tid & 63, w = tid >> 6;        // wave id 0..7
    int lrow = lane & 15, quad = lane >> 4;
    int wr2 = w & 3, wc2 = w >> 2;            // layer2 role: 32-row, 64-col tile

    // ---- B fragments direct from fp32 (L2-resident; issued first) ----------
    f16x8 bf3[8][4];  // layer3, wave strip = cols [w*128, w*128+128)
#pragma unroll
    for (int ct = 0; ct < 8; ct++)
#pragma unroll
        for (int kc = 0; kc < 4; kc++) {
            int col = w * 128 + ct * 16 + lrow;
#pragma unroll
            for (int j = 0; j < 8; j++)
                bf3[ct][kc][j] = (f16)W3[(size_t)(kc * 32 + quad * 8 + j) * 1024 + col];
        }
    f16x8 bf2[4][2];  // layer2
#pragma unroll
    for (int ct = 0; ct < 4; ct++)
#pragma unroll
        for (int kc2 = 0; kc2 < 2; kc2++) {
            int col = wc2 * 64 + ct * 16 + lrow;
#pragma unroll
            for (int j = 0; j < 8; j++)
                bf2[ct][kc2][j] = (f16)W2[(size_t)(kc2 * 32 + quad * 8 + j) * 128 + col];
        }

    // ---- stage x (whole batch), layer1 weights (staggered), b2 -------------
    {
        const float* xb = x + (size_t)b * 3072;
        for (int i = tid; i < 3072; i += 512) xs[i] = xb[i];
        if (tid < 256) {
            int k = tid >> 2, c = tid & 3;
            wls[(k + (k >> 3)) * 4 + c] = (c < 3) ? W1[c * 64 + k] : b1[k];
        }
        if (tid >= 256 && tid < 384) b2s[tid - 256] = b2[tid - 256];
    }
    __syncthreads();

    const f32x4 z4 = {0.f, 0.f, 0.f, 0.f};
    float cmax[8];
#pragma unroll
    for (int ct = 0; ct < 8; ct++) cmax[ct] = -3.0e38f;

    // phase A: layers 1+2 for `chunk` -> h2s[chunk&1]
    auto phaseA = [&](int chunk) {
        f16* hb = h2s[chunk & 1];
        int p0 = chunk * 128 + wr2 * 32 + lrow;
        float x00 = xs[p0 * 3], x01 = xs[p0 * 3 + 1], x02 = xs[p0 * 3 + 2];
        int p1 = p0 + 16;
        float x10 = xs[p1 * 3], x11 = xs[p1 * 3 + 1], x12 = xs[p1 * 3 + 2];
        f32x4 acc2[2][4];
#pragma unroll
        for (int kc2 = 0; kc2 < 2; kc2++) {
            f16x8 af2[2];
#pragma unroll
            for (int j = 0; j < 8; j++) {
                int k = kc2 * 32 + quad * 8 + j;
                f32x4 wv = *(const f32x4*)&wls[(k + (k >> 3)) * 4];
                float v0 = fmaf(x02, wv[2], fmaf(x01, wv[1], fmaf(x00, wv[0], wv[3])));
                float v1 = fmaf(x12, wv[2], fmaf(x11, wv[1], fmaf(x10, wv[0], wv[3])));
                af2[0][j] = (f16)fmaxf(v0, 0.f);
                af2[1][j] = (f16)fmaxf(v1, 0.f);
            }
#pragma unroll
            for (int rt = 0; rt < 2; rt++)
#pragma unroll
                for (int ct = 0; ct < 4; ct++)
                    acc2[rt][ct] = __builtin_amdgcn_mfma_f32_16x16x32_f16(
                        af2[rt], bf2[ct][kc2], kc2 ? acc2[rt][ct] : z4, 0, 0, 0);
        }
        // bias + relu + cvt -> LDS tile (stride 140: conflict-free b16 writes)
#pragma unroll
        for (int rt = 0; rt < 2; rt++)
#pragma unroll
            for (int ct = 0; ct < 4; ct++) {
                int col = wc2 * 64 + ct * 16 + lrow;
                float bb = b2s[col];
                int rowb = wr2 * 32 + rt * 16 + quad * 4;
#pragma unroll
                for (int r = 0; r < 4; r++)
                    hb[(rowb + r) * H2_STRIDE + col] = (f16)fmaxf(acc2[rt][ct][r] + bb, 0.f);
            }
    };

    // phase B: layer3 MFMA from h2s[chunk&1], running col-max
    auto phaseB = [&](int chunk) {
        const f16* hb = h2s[chunk & 1];
#pragma unroll
        for (int rt = 0; rt < 8; rt++) {
            f32x4 acc[8];
#pragma unroll
            for (int kc = 0; kc < 4; kc++) {
                f16x8 af = *(const f16x8*)(hb + (rt * 16 + lrow) * H2_STRIDE + kc * 32 + quad * 8);
#pragma unroll
                for (int ct = 0; ct < 8; ct++)
                    acc[ct] = __builtin_amdgcn_mfma_f32_16x16x32_f16(
                        af, bf3[ct][kc], kc ? acc[ct] : z4, 0, 0, 0);
            }
#pragma unroll
            for (int ct = 0; ct < 8; ct++) {
                float m01 = fmaxf(acc[ct][0], acc[ct][1]);
                float m23 = fmaxf(acc[ct][2], acc[ct][3]);
                cmax[ct] = fmaxf(cmax[ct], fmaxf(m01, m23));
            }
        }
    };

    phaseA(0);
    __syncthreads();
#pragma unroll 1
    for (int c = 0; c < 7; c++) {
        phaseA(c + 1);   // fills other buffer; compiler interleaves with phaseB(c)
        phaseB(c);
        __syncthreads();
    }
    phaseB(7);

    // cross-quad reduce (quads hold disjoint row subsets of same col)
#pragma unroll
    for (int ct = 0; ct < 8; ct++) {
        cmax[ct] = fmaxf(cmax[ct], __shfl_xor(cmax[ct], 16, 64));
        cmax[ct] = fmaxf(cmax[ct], __shfl_xor(cmax[ct], 32, 64));
    }
    if (quad == 0) {
#pragma unroll
        for (int ct = 0; ct < 8; ct++) {
            int cg = w * 128 + ct * 16 + lrow;
            g[(size_t)b * 1024 + cg] = fmaxf(cmax[ct] + b3[cg], 0.f);
        }
    }
}

// ---------------------------------------------------------------------------
// SVD -> SO(3) projection, fp64 Jacobi on M^T M (per-thread serial)
// ---------------------------------------------------------------------------
__device__ inline void jrot(double S[3][3], double V[3][3], int p, int q)
{
    double apq = S[p][q];
    if (fabs(apq) < 1e-36) return;
    double tau = (S[q][q] - S[p][p]) / (2.0 * apq);
    double t = (tau >= 0.0 ? 1.0 : -1.0) / (fabs(tau) + sqrt(1.0 + tau * tau));
    double c = 1.0 / sqrt(1.0 + t * t);
    double s = t * c;
    for (int k = 0; k < 3; k++) {
        double skp = S[k][p], skq = S[k][q];
        S[k][p] = c * skp - s * skq;  S[k][q] = s * skp + c * skq;
    }
    for (int k = 0; k < 3; k++) {
        double spk = S[p][k], sqk = S[q][k];
        S[p][k] = c * spk - s * sqk;  S[q][k] = s * spk + c * sqk;
    }
    for (int k = 0; k < 3; k++) {
        double vkp = V[k][p], vkq = V[k][q];
        V[k][p] = c * vkp - s * vkq;  V[k][q] = s * vkp + c * vkq;
    }
}

__device__ void svd_so3(const float* Mf, float* Rout)
{
    double M[3][3], S[3][3], V[3][3];
    for (int i = 0; i < 3; i++)
        for (int j = 0; j < 3; j++) M[i][j] = (double)Mf[3 * i + j];
    for (int i = 0; i < 3; i++)
        for (int j = 0; j < 3; j++)
            S[i][j] = M[0][i] * M[0][j] + M[1][i] * M[1][j] + M[2][i] * M[2][j];
    for (int i = 0; i < 3; i++)
        for (int j = 0; j < 3; j++) V[i][j] = (i == j) ? 1.0 : 0.0;
    for (int it = 0; it < 10; it++) {
        jrot(S, V, 0, 1); jrot(S, V, 0, 2); jrot(S, V, 1, 2);
    }
    double lam[3] = {S[0][0], S[1][1], S[2][2]};
    int i0 = 0, i1 = 1, i2 = 2, tt;
    if (lam[i0] < lam[i1]) { tt = i0; i0 = i1; i1 = tt; }
    if (lam[i0] < lam[i2]) { tt = i0; i0 = i2; i2 = tt; }
    if (lam[i1] < lam[i2]) { tt = i1; i1 = i2; i2 = tt; }
    double v0[3], v1[3], v2[3];
    for (int k = 0; k < 3; k++) { v0[k] = V[k][i0]; v1[k] = V[k][i1]; v2[k] = V[k][i2]; }
    double u1[3], u2[3], u3[3];
    for (int i = 0; i < 3; i++) u1[i] = M[i][0] * v0[0] + M[i][1] * v0[1] + M[i][2] * v0[2];
    double n1 = sqrt(u1[0] * u1[0] + u1[1] * u1[1] + u1[2] * u1[2]) + 1e-300;
    for (int i = 0; i < 3; i++) u1[i] /= n1;
    for (int i = 0; i < 3; i++) u2[i] = M[i][0] * v1[0] + M[i][1] * v1[1] + M[i][2] * v1[2];
    double d12 = u1[0] * u2[0] + u1[1] * u2[1] + u1[2] * u2[2];
    for (int i = 0; i < 3; i++) u2[i] -= d12 * u1[i];
    double n2 = sqrt(u2[0] * u2[0] + u2[1] * u2[1] + u2[2] * u2[2]) + 1e-300;
    for (int i = 0; i < 3; i++) u2[i] /= n2;
    u3[0] = u1[1] * u2[2] - u1[2] * u2[1];
    u3[1] = u1[2] * u2[0] - u1[0] * u2[2];
    u3[2] = u1[0] * u2[1] - u1[1] * u2[0];
    double c12x = v1[1] * v2[2] - v1[2] * v2[1];
    double c12y = v1[2] * v2[0] - v1[0] * v2[2];
    double c12z = v1[0] * v2[1] - v1[1] * v2[0];
    double detV = v0[0] * c12x + v0[1] * c12y + v0[2] * c12z;
    for (int i = 0; i < 3; i++)
        for (int j = 0; j < 3; j++)
            Rout[3 * i + j] = (float)(u1[i] * v0[j] + u2[i] * v1[j] + detV * u3[i] * v2[j]);
}

// ---------------------------------------------------------------------------
// Whole head in ONE kernel, ONE BATCH PER BLOCK (grid 256 = full CU coverage
// — r3's fused head failed because 128 blocks + serial K collapsed
// parallelism; this keeps 256-wide batch parallelism and L2-broadcast weight
// reads).  l1: 2 cols/thread, K=1024.  l2: 1 col/thread, K=512.  l3: 9
// threads.  SVD: thread 0.  Per-block L2 traffic = Wh1 2 MB + Wh2 0.5 MB
// ~ 18.6 us at per-CU L2 BW — replaces head_l1+head_l2+head_l3_svd plus
// their zp1/zp2 round trips and two launch gaps.
// ---------------------------------------------------------------------------
__global__ __launch_bounds__(256) void head_all(
    const float* __restrict__ g,   // [256][1024] (bias+relu applied)
    const float* __restrict__ Wh1, const float* __restrict__ bh1,
    const float* __restrict__ Wh2, const float* __restrict__ bh2,
    const float* __restrict__ Wh3, const float* __restrict__ bh3,
    float* __restrict__ out)
{
    __shared__ float gsm[1024];
    __shared__ float z1s[512];
    __shared__ float z2s[256];
    __shared__ float wh3s[2304];
    __shared__ float raw[12];

    int b = blockIdx.x;
    int tid = threadIdx.x;

    for (int i = tid; i < 1024; i += 256) gsm[i] = g[(size_t)b * 1024 + i];
    for (int i = tid; i < 2304; i += 256) wh3s[i] = Wh3[i];
    __syncthreads();

    // layer 1: cols tid and tid+256; gsm reads are wave-uniform broadcasts
    {
        float a0 = bh1[tid], a1 = bh1[tid + 256];
        const float* w0p = Wh1 + tid;
        const float* w1p = Wh1 + tid + 256;
#pragma unroll 2
        for (int k = 0; k < 1024; k += 4) {
            float4 gv = *(const float4*)&gsm[k];
            float wa0 = w0p[(size_t)(k    ) * 512], wb0 = w1p[(size_t)(k    ) * 512];
            float wa1 = w0p[(size_t)(k + 1) * 512], wb1 = w1p[(size_t)(k + 1) * 512];
            float wa2 = w0p[(size_t)(k + 2) * 512], wb2 = w1p[(size_t)(k + 2) * 512];
            float wa3 = w0p[(size_t)(k + 3) * 512], wb3 = w1p[(size_t)(k + 3) * 512];
            a0 = fmaf(gv.x, wa0, a0);  a1 = fmaf(gv.x, wb0, a1);
            a0 = fmaf(gv.y, wa1, a0);  a1 = fmaf(gv.y, wb1, a1);
            a0 = fmaf(gv.z, wa2, a0);  a1 = fmaf(gv.z, wb2, a1);
            a0 = fmaf(gv.w, wa3, a0);  a1 = fmaf(gv.w, wb3, a1);
        }
        z1s[tid]       = fmaxf(a0, 0.f);
        z1s[tid + 256] = fmaxf(a1, 0.f);
    }
    __syncthreads();

    // layer 2: col = tid
    {
        float acc = bh2[tid];
        const float* w2p = Wh2 + tid;
#pragma unroll 2
        for (int k = 0; k < 512; k += 4) {
            float4 zv = *(const float4*)&z1s[k];
            acc = fmaf(zv.x, w2p[(size_t)(k    ) * 256], acc);
            acc = fmaf(zv.y, w2p[(size_t)(k + 1) * 256], acc);
            acc = fmaf(zv.z, w2p[(size_t)(k + 2) * 256], acc);
            acc = fmaf(zv.w, w2p[(size_t)(k + 3) * 256], acc);
        }
        z2s[tid] = fmaxf(acc, 0.f);
    }
    __syncthreads();

    // layer 3: 9 outputs
    if (tid < 9) {
        float a = bh3[tid];
#pragma unroll 8
        for (int k = 0; k < 256; k++)
            a = fmaf(z2s[k], wh3s[k * 9 + tid], a);
        raw[tid] = a;
    }
    __syncthreads();

    if (tid == 0)
        svd_so3(raw, out + (size_t)b * 9);
}

// ---------------------------------------------------------------------------
extern "C" void kernel_launch(void* const* d_in, const int* in_sizes, int n_in,
                              void* d_out, int out_size, void* d_ws, size_t ws_size,
                              hipStream_t stream)
{
    const float* x   = (const float*)d_in[0];
    const float* W1  = (const float*)d_in[1];
    const float* b1  = (const float*)d_in[2];
    const float* W2  = (const float*)d_in[3];
    const float* b2  = (const float*)d_in[4];
    const float* W3  = (const float*)d_in[5];
    const float* b3  = (const float*)d_in[6];
    const float* Wh1 = (const float*)d_in[7];
    const float* bh1 = (const float*)d_in[8];
    const float* Wh2 = (const float*)d_in[9];
    const float* bh2 = (const float*)d_in[10];
    const float* Wh3 = (const float*)d_in[11];
    const float* bh3 = (const float*)d_in[12];
    float* out = (float*)d_out;

    float* g = (float*)d_ws;   // 1 MB

    pointnet_fused<<<256, 512, 0, stream>>>(x, W1, b1, W2, b2, W3, b3, g);
    head_all<<<256, 256, 0, stream>>>(g, Wh1, bh1, Wh2, bh2, Wh3, bh3, out);
}

// Round 7
// 198.708 us; speedup vs baseline: 1.4620x; 1.4620x over previous
//
#include <hip/hip_runtime.h>
#include <math.h>

typedef _Float16 f16;
typedef _Float16 f16x8 __attribute__((ext_vector_type(8)));
typedef float f32x4 __attribute__((ext_vector_type(4)));

#define H2_STRIDE 140   // f16 per LDS row: 280 B = 70 dw; 70 mod 32 = 6.
                        // phaseA b16 writes: quad dword offsets {0,24,16,8} -> conflict-free
                        //   (validated r4/r5: SQ_LDS_BANK_CONFLICT = 0).
                        // phaseB b128 reads: exactly 8 dw/bank -> minimum cycles.

// ---------------------------------------------------------------------------
// Prep: W3t[c][k] = f16(W3[k][c])  (1024x128), W2t[c][k] = f16(W2[k][c])
// (128x64), wpk[k][4] = {W1[0][k], W1[1][k], W1[2][k], b1[k]} fp32.
// LOAD-BEARING (r6 post-mortem): bf3/bf2 must be loaded as f16x8 vector
// loads straight into fragment registers.  Direct fp32+cvt in the main
// kernel makes the compiler hoist 256 scalar loads -> ~110 regs spilled,
// 58 MB scratch writes/launch, 70->131 us.
// ---------------------------------------------------------------------------
__global__ __launch_bounds__(256) void prep_weights(
    const float* __restrict__ W1, const float* __restrict__ b1,
    const float* __restrict__ W2, const float* __restrict__ W3,
    f16* __restrict__ W2t, f16* __restrict__ W3t, float* __restrict__ wpk)
{
    int idx = blockIdx.x * 256 + threadIdx.x;
    int stride = gridDim.x * 256;
    for (int i = idx; i < 1024 * 128; i += stride) {
        int c = i >> 7, k = i & 127;
        W3t[i] = (f16)W3[k * 1024 + c];
    }
    for (int i = idx; i < 128 * 64; i += stride) {
        int c = i >> 6, k = i & 63;
        W2t[i] = (f16)W2[k * 128 + c];
    }
    if (idx < 256) {
        int k = idx >> 2, c = idx & 3;
        wpk[idx] = (c < 3) ? W1[c * 64 + k] : b1[k];
    }
}

// ---------------------------------------------------------------------------
// Fused PointNet: layers 1-3 + max-pool, one block per batch (grid = 256 =
// 1 block/CU).  512 threads = 8 waves.  EXACT r1-measured structure (70.4 us)
// with only the validated stride-140 change.
// REGISTER DISCIPLINE (r2/r4/r6): bf3 = 128 VGPRs resident =>
//  (a) __launch_bounds__(512, 2) required;
//  (b) 1 barrier per chunk (wider windows extend live ranges -> spill);
//  (c) fragments loaded via f16x8 vector loads from W3t/W2t (see prep).
// NO s_setprio (r5: −23 us; starved phaseA waves' VALU issue).
// ---------------------------------------------------------------------------
__global__ __launch_bounds__(512, 2) void pointnet_fused(
    const float* __restrict__ x,   // [B][1024][3]
    const float* __restrict__ wpk, // [64][4] {w0,w1,w2,b1}
    const f16* __restrict__ W2t,   // [128 c][64 k]
    const float* __restrict__ b2,  // [128]
    const f16* __restrict__ W3t,   // [1024 c][128 k]
    const float* __restrict__ b3,  // [1024]
    float* __restrict__ g)         // [B][1024]
{
    __shared__ float xs[1024 * 3];                        // 12 KB, whole batch
    __shared__ __align__(16) float wls[288];              // staggered W1+b1 pack
    __shared__ float b2s[128];
    __shared__ __align__(16) f16 h2s[2][128 * H2_STRIDE]; // 2 x 35 KB

    int b = blockIdx.x;
    int tid = threadIdx.x;
    int lane = tid & 63, w = tid >> 6;        // wave id 0..7
    int lrow = lane & 15, quad = lane >> 4;
    int wr2 = w & 3, wc2 = w >> 2;            // layer2 role: 32-row, 64-col tile

    // ---- B fragments issued first: latency hides under staging -------------
    f16x8 bf3[8][4];  // layer3, wave strip = cols [w*128, w*128+128)
    {
        const f16* base = W3t + (size_t)(w * 128 + lrow) * 128 + quad * 8;
#pragma unroll
        for (int ct = 0; ct < 8; ct++)
#pragma unroll
            for (int kc = 0; kc < 4; kc++)
                bf3[ct][kc] = *(const f16x8*)(base + ct * 16 * 128 + kc * 32);
    }
    f16x8 bf2[4][2];  // layer2
    {
        const f16* base = W2t + (size_t)(wc2 * 64 + lrow) * 64 + quad * 8;
#pragma unroll
        for (int ct = 0; ct < 4; ct++)
#pragma unroll
            for (int kc2 = 0; kc2 < 2; kc2++)
                bf2[ct][kc2] = *(const f16x8*)(base + ct * 16 * 64 + kc2 * 32);
    }

    // ---- stage x (whole batch), layer1 weights (staggered), b2 -------------
    {
        const float* xb = x + (size_t)b * 3072;
        for (int i = tid; i < 3072; i += 512) xs[i] = xb[i];
        if (tid < 256) {
            int k = tid >> 2, c = tid & 3;
            wls[(k + (k >> 3)) * 4 + c] = wpk[tid];
        }
        if (tid >= 256 && tid < 384) b2s[tid - 256] = b2[tid - 256];
    }
    __syncthreads();

    const f32x4 z4 = {0.f, 0.f, 0.f, 0.f};
    float cmax[8];
#pragma unroll
    for (int ct = 0; ct < 8; ct++) cmax[ct] = -3.0e38f;

    // phase A: layers 1+2 for `chunk` -> h2s[chunk&1]
    auto phaseA = [&](int chunk) {
        f16* hb = h2s[chunk & 1];
        int p0 = chunk * 128 + wr2 * 32 + lrow;
        float x00 = xs[p0 * 3], x01 = xs[p0 * 3 + 1], x02 = xs[p0 * 3 + 2];
        int p1 = p0 + 16;
        float x10 = xs[p1 * 3], x11 = xs[p1 * 3 + 1], x12 = xs[p1 * 3 + 2];
        f32x4 acc2[2][4];
#pragma unroll
        for (int kc2 = 0; kc2 < 2; kc2++) {
            f16x8 af2[2];
#pragma unroll
            for (int j = 0; j < 8; j++) {
                int k = kc2 * 32 + quad * 8 + j;
                f32x4 wv = *(const f32x4*)&wls[(k + (k >> 3)) * 4];
                float v0 = fmaf(x02, wv[2], fmaf(x01, wv[1], fmaf(x00, wv[0], wv[3])));
                float v1 = fmaf(x12, wv[2], fmaf(x11, wv[1], fmaf(x10, wv[0], wv[3])));
                af2[0][j] = (f16)fmaxf(v0, 0.f);
                af2[1][j] = (f16)fmaxf(v1, 0.f);
            }
#pragma unroll
            for (int rt = 0; rt < 2; rt++)
#pragma unroll
                for (int ct = 0; ct < 4; ct++)
                    acc2[rt][ct] = __builtin_amdgcn_mfma_f32_16x16x32_f16(
                        af2[rt], bf2[ct][kc2], kc2 ? acc2[rt][ct] : z4, 0, 0, 0);
        }
        // bias + relu + cvt -> LDS tile (stride 140: conflict-free b16 writes)
#pragma unroll
        for (int rt = 0; rt < 2; rt++)
#pragma unroll
            for (int ct = 0; ct < 4; ct++) {
                int col = wc2 * 64 + ct * 16 + lrow;
                float bb = b2s[col];
                int rowb = wr2 * 32 + rt * 16 + quad * 4;
#pragma unroll
                for (int r = 0; r < 4; r++)
                    hb[(rowb + r) * H2_STRIDE + col] = (f16)fmaxf(acc2[rt][ct][r] + bb, 0.f);
            }
    };

    // phase B: layer3 MFMA from h2s[chunk&1], running col-max
    auto phaseB = [&](int chunk) {
        const f16* hb = h2s[chunk & 1];
#pragma unroll
        for (int rt = 0; rt < 8; rt++) {
            f32x4 acc[8];
#pragma unroll
            for (int kc = 0; kc < 4; kc++) {
                f16x8 af = *(const f16x8*)(hb + (rt * 16 + lrow) * H2_STRIDE + kc * 32 + quad * 8);
#pragma unroll
                for (int ct = 0; ct < 8; ct++)
                    acc[ct] = __builtin_amdgcn_mfma_f32_16x16x32_f16(
                        af, bf3[ct][kc], kc ? acc[ct] : z4, 0, 0, 0);
            }
#pragma unroll
            for (int ct = 0; ct < 8; ct++) {
                float m01 = fmaxf(acc[ct][0], acc[ct][1]);
                float m23 = fmaxf(acc[ct][2], acc[ct][3]);
                cmax[ct] = fmaxf(cmax[ct], fmaxf(m01, m23));
            }
        }
    };

    phaseA(0);
    __syncthreads();
#pragma unroll 1
    for (int c = 0; c < 7; c++) {
        phaseA(c + 1);   // fills other buffer; compiler interleaves with phaseB(c)
        phaseB(c);
        __syncthreads();
    }
    phaseB(7);

    // cross-quad reduce (quads hold disjoint row subsets of same col)
#pragma unroll
    for (int ct = 0; ct < 8; ct++) {
        cmax[ct] = fmaxf(cmax[ct], __shfl_xor(cmax[ct], 16, 64));
        cmax[ct] = fmaxf(cmax[ct], __shfl_xor(cmax[ct], 32, 64));
    }
    if (quad == 0) {
#pragma unroll
        for (int ct = 0; ct < 8; ct++) {
            int cg = w * 128 + ct * 16 + lrow;
            g[(size_t)b * 1024 + cg] = fmaxf(cmax[ct] + b3[cg], 0.f);
        }
    }
}

// ---------------------------------------------------------------------------
// SVD -> SO(3) projection, fp64 Jacobi on M^T M (per-thread serial)
// ---------------------------------------------------------------------------
__device__ inline void jrot(double S[3][3], double V[3][3], int p, int q)
{
    double apq = S[p][q];
    if (fabs(apq) < 1e-36) return;
    double tau = (S[q][q] - S[p][p]) / (2.0 * apq);
    double t = (tau >= 0.0 ? 1.0 : -1.0) / (fabs(tau) + sqrt(1.0 + tau * tau));
    double c = 1.0 / sqrt(1.0 + t * t);
    double s = t * c;
    for (int k = 0; k < 3; k++) {
        double skp = S[k][p], skq = S[k][q];
        S[k][p] = c * skp - s * skq;  S[k][q] = s * skp + c * skq;
    }
    for (int k = 0; k < 3; k++) {
        double spk = S[p][k], sqk = S[q][k];
        S[p][k] = c * spk - s * sqk;  S[q][k] = s * spk + c * sqk;
    }
    for (int k = 0; k < 3; k++) {
        double vkp = V[k][p], vkq = V[k][q];
        V[k][p] = c * vkp - s * vkq;  V[k][q] = s * vkp + c * vkq;
    }
}

__device__ void svd_so3(const float* Mf, float* Rout)
{
    double M[3][3], S[3][3], V[3][3];
    for (int i = 0; i < 3; i++)
        for (int j = 0; j < 3; j++) M[i][j] = (double)Mf[3 * i + j];
    for (int i = 0; i < 3; i++)
        for (int j = 0; j < 3; j++)
            S[i][j] = M[0][i] * M[0][j] + M[1][i] * M[1][j] + M[2][i] * M[2][j];
    for (int i = 0; i < 3; i++)
        for (int j = 0; j < 3; j++) V[i][j] = (i == j) ? 1.0 : 0.0;
    for (int it = 0; it < 10; it++) {
        jrot(S, V, 0, 1); jrot(S, V, 0, 2); jrot(S, V, 1, 2);
    }
    double lam[3] = {S[0][0], S[1][1], S[2][2]};
    int i0 = 0, i1 = 1, i2 = 2, tt;
    if (lam[i0] < lam[i1]) { tt = i0; i0 = i1; i1 = tt; }
    if (lam[i0] < lam[i2]) { tt = i0; i0 = i2; i2 = tt; }
    if (lam[i1] < lam[i2]) { tt = i1; i1 = i2; i2 = tt; }
    double v0[3], v1[3], v2[3];
    for (int k = 0; k < 3; k++) { v0[k] = V[k][i0]; v1[k] = V[k][i1]; v2[k] = V[k][i2]; }
    double u1[3], u2[3], u3[3];
    for (int i = 0; i < 3; i++) u1[i] = M[i][0] * v0[0] + M[i][1] * v0[1] + M[i][2] * v0[2];
    double n1 = sqrt(u1[0] * u1[0] + u1[1] * u1[1] + u1[2] * u1[2]) + 1e-300;
    for (int i = 0; i < 3; i++) u1[i] /= n1;
    for (int i = 0; i < 3; i++) u2[i] = M[i][0] * v1[0] + M[i][1] * v1[1] + M[i][2] * v1[2];
    double d12 = u1[0] * u2[0] + u1[1] * u2[1] + u1[2] * u2[2];
    for (int i = 0; i < 3; i++) u2[i] -= d12 * u1[i];
    double n2 = sqrt(u2[0] * u2[0] + u2[1] * u2[1] + u2[2] * u2[2]) + 1e-300;
    for (int i = 0; i < 3; i++) u2[i] /= n2;
    u3[0] = u1[1] * u2[2] - u1[2] * u2[1];
    u3[1] = u1[2] * u2[0] - u1[0] * u2[2];
    u3[2] = u1[0] * u2[1] - u1[1] * u2[0];
    double c12x = v1[1] * v2[2] - v1[2] * v2[1];
    double c12y = v1[2] * v2[0] - v1[0] * v2[2];
    double c12z = v1[0] * v2[1] - v1[1] * v2[0];
    double detV = v0[0] * c12x + v0[1] * c12y + v0[2] * c12z;
    for (int i = 0; i < 3; i++)
        for (int j = 0; j < 3; j++)
            Rout[3 * i + j] = (float)(u1[i] * v0[j] + u2[i] * v1[j] + detV * u3[i] * v2[j]);
}

// ---------------------------------------------------------------------------
// Whole head, ONE kernel, one batch per block (grid 256 = full CU coverage),
// 512 threads.  Fix for r3/r6 fused-head failures: K-SPLIT INSIDE THE BLOCK.
//  l1: thread = (kslice ks=tid>>7 of 4, colgroup cg=tid&127 -> 4 cols via
//      float4 weight loads).  256 iters/thread, 1 KB/wave/load instr,
//      64 load-instrs in flight per CU -> L2-BW-bound (~19 us), NOT
//      latency-bound like the serial-K versions.
//  l2: 8 kslices x 64 colgroups.  l3: 16 kslices x 9 cols.  SVD: thread 0.
//  LDS partial-reduce between layers; identical math, k-split order.
// ---------------------------------------------------------------------------
__global__ __launch_bounds__(512) void head_one(
    const float* __restrict__ g,   // [256][1024] (bias+relu applied)
    const float* __restrict__ Wh1, const float* __restrict__ bh1,
    const float* __restrict__ Wh2, const float* __restrict__ bh2,
    const float* __restrict__ Wh3, const float* __restrict__ bh3,
    float* __restrict__ out)
{
    __shared__ float gsm[1024];            // 4 KB
    __shared__ float z1p[4][512];          // 8 KB partials
    __shared__ float z1s[512];             // 2 KB
    __shared__ float z2p[8][256];          // 8 KB partials
    __shared__ float z2s[256];             // 1 KB
    __shared__ float l3p[16][9];
    __shared__ float wh3s[2304];           // 9.2 KB
    __shared__ float raw[12];

    int b = blockIdx.x;
    int tid = threadIdx.x;

    for (int i = tid; i < 1024; i += 512) gsm[i] = g[(size_t)b * 1024 + i];
    for (int i = tid; i < 2304; i += 512) wh3s[i] = Wh3[i];
    __syncthreads();

    // ---- layer 1: z1[512] = relu(g @ Wh1 + bh1), 4-way k-split -------------
    {
        int cg = tid & 127;        // cols 4cg..4cg+3
        int ks = tid >> 7;         // k-slice 0..3, K=256 each
        int k0 = ks * 256;
        f32x4 acc = {0.f, 0.f, 0.f, 0.f};
        const float* wp = Wh1 + (size_t)k0 * 512 + cg * 4;
#pragma unroll 8
        for (int k = 0; k < 256; k++) {
            f32x4 wv = *(const f32x4*)(wp + (size_t)k * 512);
            float gk = gsm[k0 + k];                 // wave-uniform broadcast
            acc[0] = fmaf(gk, wv[0], acc[0]);
            acc[1] = fmaf(gk, wv[1], acc[1]);
            acc[2] = fmaf(gk, wv[2], acc[2]);
            acc[3] = fmaf(gk, wv[3], acc[3]);
        }
        *(f32x4*)&z1p[ks][cg * 4] = acc;
    }
    __syncthreads();
    {
        float v = bh1[tid & 511];
        int col = tid & 511;
        if (tid < 512) {
            v += z1p[0][col] + z1p[1][col] + z1p[2][col] + z1p[3][col];
            z1s[col] = fmaxf(v, 0.f);
        }
    }
    __syncthreads();

    // ---- layer 2: z2[256] = relu(z1 @ Wh2 + bh2), 8-way k-split ------------
    {
        int cg = tid & 63;         // cols 4cg..4cg+3
        int ks = tid >> 6;         // k-slice 0..7, K=64 each
        int k0 = ks * 64;
        f32x4 acc = {0.f, 0.f, 0.f, 0.f};
        const float* wp = Wh2 + (size_t)k0 * 256 + cg * 4;
#pragma unroll 8
        for (int k = 0; k < 64; k++) {
            f32x4 wv = *(const f32x4*)(wp + (size_t)k * 256);
            float zk = z1s[k0 + k];
            acc[0] = fmaf(zk, wv[0], acc[0]);
            acc[1] = fmaf(zk, wv[1], acc[1]);
            acc[2] = fmaf(zk, wv[2], acc[2]);
            acc[3] = fmaf(zk, wv[3], acc[3]);
        }
        *(f32x4*)&z2p[ks][cg * 4] = acc;
    }
    __syncthreads();
    if (tid < 256) {
        float v = bh2[tid];
#pragma unroll
        for (int j = 0; j < 8; j++) v += z2p[j][tid];
        z2s[tid] = fmaxf(v, 0.f);
    }
    __syncthreads();

    // ---- layer 3: raw[9] = z2 @ Wh3 + bh3, 16-way k-split ------------------
    if (tid < 144) {
        int c = tid % 9, ks = tid / 9;     // K=16 each
        float a = 0.f;
#pragma unroll
        for (int k = 0; k < 16; k++)
            a = fmaf(z2s[ks * 16 + k], wh3s[(ks * 16 + k) * 9 + c], a);
        l3p[ks][c] = a;
    }
    __syncthreads();
    if (tid < 9) {
        float a = bh3[tid];
#pragma unroll
        for (int j = 0; j < 16; j++) a += l3p[j][tid];
        raw[tid] = a;
    }
    __syncthreads();

    if (tid == 0)
        svd_so3(raw, out + (size_t)b * 9);
}

// ---------------------------------------------------------------------------
extern "C" void kernel_launch(void* const* d_in, const int* in_sizes, int n_in,
                              void* d_out, int out_size, void* d_ws, size_t ws_size,
                              hipStream_t stream)
{
    const float* x   = (const float*)d_in[0];
    const float* W1  = (const float*)d_in[1];
    const float* b1  = (const float*)d_in[2];
    const float* W2  = (const float*)d_in[3];
    const float* b2  = (const float*)d_in[4];
    const float* W3  = (const float*)d_in[5];
    const float* b3  = (const float*)d_in[6];
    const float* Wh1 = (const float*)d_in[7];
    const float* bh1 = (const float*)d_in[8];
    const float* Wh2 = (const float*)d_in[9];
    const float* bh2 = (const float*)d_in[10];
    const float* Wh3 = (const float*)d_in[11];
    const float* bh3 = (const float*)d_in[12];
    float* out = (float*)d_out;

    char* ws = (char*)d_ws;
    f16*   W2t = (f16*)ws;                  // 16 KB
    f16*   W3t = (f16*)(ws + 65536);        // 256 KB
    float* wpk = (float*)(ws + 524288);     // 1 KB
    float* g   = (float*)(ws + 1048576);    // 1 MB

    prep_weights<<<128, 256, 0, stream>>>(W1, b1, W2, W3, W2t, W3t, wpk);
    pointnet_fused<<<256, 512, 0, stream>>>(x, wpk, W2t, b2, W3t, b3, g);
    head_one<<<256, 512, 0, stream>>>(g, Wh1, bh1, Wh2, bh2, Wh3, bh3, out);
}

// Round 8
// 172.532 us; speedup vs baseline: 1.6838x; 1.1517x over previous
//
#include <hip/hip_runtime.h>
#include <math.h>

typedef _Float16 f16;
typedef _Float16 f16x8 __attribute__((ext_vector_type(8)));
typedef float f32x4 __attribute__((ext_vector_type(4)));

#define H2_STRIDE 136   // f16 per row = 272 B = 17x16 -> EVERY row 16-B aligned.
// STRIDE ERRATA (r5/r7 post-mortem): stride 140 (280 B) leaves odd rows only
// 8-B aligned -> ds_read_b128 splits -> +24 us (70.4 -> 93-94, two independent
// measurements), even though bank conflicts = 0.  No stride fixes both: any
// 16-B-aligned stride has quad write offsets 2S*q mod 32 in {0,16} -> >=4-way
// write aliasing.  136 keeps alignment; the 2.1M write-conflict cycles
// (~3.4 us/CU) are mostly hidden under phaseB MFMA.  DO NOT CHANGE.

// ---------------------------------------------------------------------------
// Prep: W3t[c][k] = f16(W3[k][c])  (1024x128), W2t[c][k] = f16(W2[k][c])
// (128x64), wpk[k][4] = {W1[0][k], W1[1][k], W1[2][k], b1[k]} fp32.
// LOAD-BEARING (r6): bf3/bf2 must be f16x8 vector loads straight into
// fragment registers; direct fp32+cvt in the main kernel spills ~110 regs.
// ---------------------------------------------------------------------------
__global__ __launch_bounds__(256) void prep_weights(
    const float* __restrict__ W1, const float* __restrict__ b1,
    const float* __restrict__ W2, const float* __restrict__ W3,
    f16* __restrict__ W2t, f16* __restrict__ W3t, float* __restrict__ wpk)
{
    int idx = blockIdx.x * 256 + threadIdx.x;
    int stride = gridDim.x * 256;
    for (int i = idx; i < 1024 * 128; i += stride) {
        int c = i >> 7, k = i & 127;
        W3t[i] = (f16)W3[k * 1024 + c];
    }
    for (int i = idx; i < 128 * 64; i += stride) {
        int c = i >> 6, k = i & 63;
        W2t[i] = (f16)W2[k * 128 + c];
    }
    if (idx < 256) {
        int k = idx >> 2, c = idx & 3;
        wpk[idx] = (c < 3) ? W1[c * 64 + k] : b1[k];
    }
}

// ---------------------------------------------------------------------------
// Fused PointNet: layers 1-3 + max-pool, one block per batch (grid = 256 =
// 1 block/CU).  512 threads = 8 waves.  EXACT r1-measured structure (70.4 us).
// REGISTER DISCIPLINE (r2/r4/r6): bf3 = 128 VGPRs resident =>
//  (a) __launch_bounds__(512, 2) required;
//  (b) 1 barrier per chunk (wider windows extend live ranges -> spill);
//  (c) fragments via f16x8 vector loads from W3t/W2t.
// NO s_setprio (r5/r7: neutral-to-negative on this lockstep structure; m190).
// ---------------------------------------------------------------------------
__global__ __launch_bounds__(512, 2) void pointnet_fused(
    const float* __restrict__ x,   // [B][1024][3]
    const float* __restrict__ wpk, // [64][4] {w0,w1,w2,b1}
    const f16* __restrict__ W2t,   // [128 c][64 k]
    const float* __restrict__ b2,  // [128]
    const f16* __restrict__ W3t,   // [1024 c][128 k]
    const float* __restrict__ b3,  // [1024]
    float* __restrict__ g)         // [B][1024]
{
    __shared__ float xs[1024 * 3];                        // 12 KB, whole batch
    __shared__ __align__(16) float wls[288];              // staggered W1+b1 pack
    __shared__ float b2s[128];
    __shared__ __align__(16) f16 h2s[2][128 * H2_STRIDE]; // 2 x 34 KB

    int b = blockIdx.x;
    int tid = threadIdx.x;
    int lane = tid & 63, w = tid >> 6;        // wave id 0..7
    int lrow = lane & 15, quad = lane >> 4;
    int wr2 = w & 3, wc2 = w >> 2;            // layer2 role: 32-row, 64-col tile

    // ---- B fragments issued first: latency hides under staging -------------
    f16x8 bf3[8][4];  // layer3, wave strip = cols [w*128, w*128+128)
    {
        const f16* base = W3t + (size_t)(w * 128 + lrow) * 128 + quad * 8;
#pragma unroll
        for (int ct = 0; ct < 8; ct++)
#pragma unroll
            for (int kc = 0; kc < 4; kc++)
                bf3[ct][kc] = *(const f16x8*)(base + ct * 16 * 128 + kc * 32);
    }
    f16x8 bf2[4][2];  // layer2
    {
        const f16* base = W2t + (size_t)(wc2 * 64 + lrow) * 64 + quad * 8;
#pragma unroll
        for (int ct = 0; ct < 4; ct++)
#pragma unroll
            for (int kc2 = 0; kc2 < 2; kc2++)
                bf2[ct][kc2] = *(const f16x8*)(base + ct * 16 * 64 + kc2 * 32);
    }

    // ---- stage x (whole batch), layer1 weights (staggered), b2 -------------
    {
        const float* xb = x + (size_t)b * 3072;
        for (int i = tid; i < 3072; i += 512) xs[i] = xb[i];
        if (tid < 256) {
            int k = tid >> 2, c = tid & 3;
            wls[(k + (k >> 3)) * 4 + c] = wpk[tid];
        }
        if (tid >= 256 && tid < 384) b2s[tid - 256] = b2[tid - 256];
    }
    __syncthreads();

    const f32x4 z4 = {0.f, 0.f, 0.f, 0.f};
    float cmax[8];
#pragma unroll
    for (int ct = 0; ct < 8; ct++) cmax[ct] = -3.0e38f;

    // phase A: layers 1+2 for `chunk` -> h2s[chunk&1]
    auto phaseA = [&](int chunk) {
        f16* hb = h2s[chunk & 1];
        int p0 = chunk * 128 + wr2 * 32 + lrow;
        float x00 = xs[p0 * 3], x01 = xs[p0 * 3 + 1], x02 = xs[p0 * 3 + 2];
        int p1 = p0 + 16;
        float x10 = xs[p1 * 3], x11 = xs[p1 * 3 + 1], x12 = xs[p1 * 3 + 2];
        f32x4 acc2[2][4];
#pragma unroll
        for (int kc2 = 0; kc2 < 2; kc2++) {
            f16x8 af2[2];
#pragma unroll
            for (int j = 0; j < 8; j++) {
                int k = kc2 * 32 + quad * 8 + j;
                f32x4 wv = *(const f32x4*)&wls[(k + (k >> 3)) * 4];
                float v0 = fmaf(x02, wv[2], fmaf(x01, wv[1], fmaf(x00, wv[0], wv[3])));
                float v1 = fmaf(x12, wv[2], fmaf(x11, wv[1], fmaf(x10, wv[0], wv[3])));
                af2[0][j] = (f16)fmaxf(v0, 0.f);
                af2[1][j] = (f16)fmaxf(v1, 0.f);
            }
#pragma unroll
            for (int rt = 0; rt < 2; rt++)
#pragma unroll
                for (int ct = 0; ct < 4; ct++)
                    acc2[rt][ct] = __builtin_amdgcn_mfma_f32_16x16x32_f16(
                        af2[rt], bf2[ct][kc2], kc2 ? acc2[rt][ct] : z4, 0, 0, 0);
        }
        // bias + relu + cvt -> LDS tile
#pragma unroll
        for (int rt = 0; rt < 2; rt++)
#pragma unroll
            for (int ct = 0; ct < 4; ct++) {
                int col = wc2 * 64 + ct * 16 + lrow;
                float bb = b2s[col];
                int rowb = wr2 * 32 + rt * 16 + quad * 4;
#pragma unroll
                for (int r = 0; r < 4; r++)
                    hb[(rowb + r) * H2_STRIDE + col] = (f16)fmaxf(acc2[rt][ct][r] + bb, 0.f);
            }
    };

    // phase B: layer3 MFMA from h2s[chunk&1], running col-max
    auto phaseB = [&](int chunk) {
        const f16* hb = h2s[chunk & 1];
#pragma unroll
        for (int rt = 0; rt < 8; rt++) {
            f32x4 acc[8];
#pragma unroll
            for (int kc = 0; kc < 4; kc++) {
                f16x8 af = *(const f16x8*)(hb + (rt * 16 + lrow) * H2_STRIDE + kc * 32 + quad * 8);
#pragma unroll
                for (int ct = 0; ct < 8; ct++)
                    acc[ct] = __builtin_amdgcn_mfma_f32_16x16x32_f16(
                        af, bf3[ct][kc], kc ? acc[ct] : z4, 0, 0, 0);
            }
#pragma unroll
            for (int ct = 0; ct < 8; ct++) {
                float m01 = fmaxf(acc[ct][0], acc[ct][1]);
                float m23 = fmaxf(acc[ct][2], acc[ct][3]);
                cmax[ct] = fmaxf(cmax[ct], fmaxf(m01, m23));
            }
        }
    };

    phaseA(0);
    __syncthreads();
#pragma unroll 1
    for (int c = 0; c < 7; c++) {
        phaseA(c + 1);   // fills other buffer; compiler interleaves with phaseB(c)
        phaseB(c);
        __syncthreads();
    }
    phaseB(7);

    // cross-quad reduce (quads hold disjoint row subsets of same col)
#pragma unroll
    for (int ct = 0; ct < 8; ct++) {
        cmax[ct] = fmaxf(cmax[ct], __shfl_xor(cmax[ct], 16, 64));
        cmax[ct] = fmaxf(cmax[ct], __shfl_xor(cmax[ct], 32, 64));
    }
    if (quad == 0) {
#pragma unroll
        for (int ct = 0; ct < 8; ct++) {
            int cg = w * 128 + ct * 16 + lrow;
            g[(size_t)b * 1024 + cg] = fmaxf(cmax[ct] + b3[cg], 0.f);
        }
    }
}

// ---------------------------------------------------------------------------
// SVD -> SO(3) projection, fp64 Jacobi on M^T M (per-thread serial)
// ---------------------------------------------------------------------------
__device__ inline void jrot(double S[3][3], double V[3][3], int p, int q)
{
    double apq = S[p][q];
    if (fabs(apq) < 1e-36) return;
    double tau = (S[q][q] - S[p][p]) / (2.0 * apq);
    double t = (tau >= 0.0 ? 1.0 : -1.0) / (fabs(tau) + sqrt(1.0 + tau * tau));
    double c = 1.0 / sqrt(1.0 + t * t);
    double s = t * c;
    for (int k = 0; k < 3; k++) {
        double skp = S[k][p], skq = S[k][q];
        S[k][p] = c * skp - s * skq;  S[k][q] = s * skp + c * skq;
    }
    for (int k = 0; k < 3; k++) {
        double spk = S[p][k], sqk = S[q][k];
        S[p][k] = c * spk - s * sqk;  S[q][k] = s * spk + c * sqk;
    }
    for (int k = 0; k < 3; k++) {
        double vkp = V[k][p], vkq = V[k][q];
        V[k][p] = c * vkp - s * vkq;  V[k][q] = s * vkp + c * vkq;
    }
}

__device__ void svd_so3(const float* Mf, float* Rout)
{
    double M[3][3], S[3][3], V[3][3];
    for (int i = 0; i < 3; i++)
        for (int j = 0; j < 3; j++) M[i][j] = (double)Mf[3 * i + j];
    for (int i = 0; i < 3; i++)
        for (int j = 0; j < 3; j++)
            S[i][j] = M[0][i] * M[0][j] + M[1][i] * M[1][j] + M[2][i] * M[2][j];
    for (int i = 0; i < 3; i++)
        for (int j = 0; j < 3; j++) V[i][j] = (i == j) ? 1.0 : 0.0;
    for (int it = 0; it < 10; it++) {
        jrot(S, V, 0, 1); jrot(S, V, 0, 2); jrot(S, V, 1, 2);
    }
    double lam[3] = {S[0][0], S[1][1], S[2][2]};
    int i0 = 0, i1 = 1, i2 = 2, tt;
    if (lam[i0] < lam[i1]) { tt = i0; i0 = i1; i1 = tt; }
    if (lam[i0] < lam[i2]) { tt = i0; i0 = i2; i2 = tt; }
    if (lam[i1] < lam[i2]) { tt = i1; i1 = i2; i2 = tt; }
    double v0[3], v1[3], v2[3];
    for (int k = 0; k < 3; k++) { v0[k] = V[k][i0]; v1[k] = V[k][i1]; v2[k] = V[k][i2]; }
    double u1[3], u2[3], u3[3];
    for (int i = 0; i < 3; i++) u1[i] = M[i][0] * v0[0] + M[i][1] * v0[1] + M[i][2] * v0[2];
    double n1 = sqrt(u1[0] * u1[0] + u1[1] * u1[1] + u1[2] * u1[2]) + 1e-300;
    for (int i = 0; i < 3; i++) u1[i] /= n1;
    for (int i = 0; i < 3; i++) u2[i] = M[i][0] * v1[0] + M[i][1] * v1[1] + M[i][2] * v1[2];
    double d12 = u1[0] * u2[0] + u1[1] * u2[1] + u1[2] * u2[2];
    for (int i = 0; i < 3; i++) u2[i] -= d12 * u1[i];
    double n2 = sqrt(u2[0] * u2[0] + u2[1] * u2[1] + u2[2] * u2[2]) + 1e-300;
    for (int i = 0; i < 3; i++) u2[i] /= n2;
    u3[0] = u1[1] * u2[2] - u1[2] * u2[1];
    u3[1] = u1[2] * u2[0] - u1[0] * u2[2];
    u3[2] = u1[0] * u2[1] - u1[1] * u2[0];
    double c12x = v1[1] * v2[2] - v1[2] * v2[1];
    double c12y = v1[2] * v2[0] - v1[0] * v2[2];
    double c12z = v1[0] * v2[1] - v1[1] * v2[0];
    double detV = v0[0] * c12x + v0[1] * c12y + v0[2] * c12z;
    for (int i = 0; i < 3; i++)
        for (int j = 0; j < 3; j++)
            Rout[3 * i + j] = (float)(u1[i] * v0[j] + u2[i] * v1[j] + detV * u3[i] * v2[j]);
}

// ---------------------------------------------------------------------------
// Head, one kernel: 128 blocks x 2 batches, 512 threads, k-split per layer.
// Fix for head_one's ~80 us (r7 inference; L2 model said 19):
//  (1) 2 batches/block halves total weight traffic (each Wh1/Wh2 load feeds
//      2 batches' FMAs);
//  (2) PER-BLOCK K-ROTATION: all blocks previously walked identical Wh1
//      addresses in lockstep -> all 32 CUs/XCD hammer the same L2 lines/banks
//      at the same instant, collapsing effective L2 BW.  Block-dependent
//      start offset (131*b mod 256) de-phases the streams.  Reorders the
//      k-accumulation only (fp32 sum reorder, ~ulp effect).
// ---------------------------------------------------------------------------
__global__ __launch_bounds__(512) void head_batched(
    const float* __restrict__ g,   // [256][1024] (bias+relu applied)
    const float* __restrict__ Wh1, const float* __restrict__ bh1,
    const float* __restrict__ Wh2, const float* __restrict__ bh2,
    const float* __restrict__ Wh3, const float* __restrict__ bh3,
    float* __restrict__ out)
{
    __shared__ float gsm[2][1024];      // 8 KB
    __shared__ float z1p[4][2][512];    // 16 KB partials
    __shared__ float z1s[2][512];       // 4 KB
    __shared__ float z2p[8][2][256];    // 16 KB partials
    __shared__ float z2s[2][256];       // 2 KB
    __shared__ float l3p[16][2][9];
    __shared__ float wh3s[2304];        // 9 KB
    __shared__ float raw[2][12];

    int b0 = blockIdx.x * 2;
    int tid = threadIdx.x;
    int roff = (blockIdx.x * 131) & 255;   // de-phase L2 streams across CUs

    for (int i = tid; i < 2048; i += 512)
        gsm[i >> 10][i & 1023] = g[(size_t)(b0 + (i >> 10)) * 1024 + (i & 1023)];
    for (int i = tid; i < 2304; i += 512) wh3s[i] = Wh3[i];
    __syncthreads();

    // ---- layer 1: z1[2][512], 4-way k-split, rotated k-walk -----------------
    {
        int cg = tid & 127;        // cols 4cg..4cg+3
        int ks = tid >> 7;         // k-slice 0..3, K=256 each
        int k0 = ks * 256;
        f32x4 a0 = {0.f, 0.f, 0.f, 0.f}, a1 = {0.f, 0.f, 0.f, 0.f};
        const float* wp = Wh1 + cg * 4;
#pragma unroll 4
        for (int kk = 0; kk < 256; kk++) {
            int k = k0 + ((kk + roff) & 255);
            f32x4 wv = *(const f32x4*)(wp + (size_t)k * 512);
            float g0 = gsm[0][k], g1 = gsm[1][k];   // LDS broadcast
            a0[0] = fmaf(g0, wv[0], a0[0]);  a1[0] = fmaf(g1, wv[0], a1[0]);
            a0[1] = fmaf(g0, wv[1], a0[1]);  a1[1] = fmaf(g1, wv[1], a1[1]);
            a0[2] = fmaf(g0, wv[2], a0[2]);  a1[2] = fmaf(g1, wv[2], a1[2]);
            a0[3] = fmaf(g0, wv[3], a0[3]);  a1[3] = fmaf(g1, wv[3], a1[3]);
        }
        *(f32x4*)&z1p[ks][0][cg * 4] = a0;
        *(f32x4*)&z1p[ks][1][cg * 4] = a1;
    }
    __syncthreads();
    for (int i = tid; i < 1024; i += 512) {
        int r = i >> 9, col = i & 511;
        float v = bh1[col] + z1p[0][r][col] + z1p[1][r][col]
                           + z1p[2][r][col] + z1p[3][r][col];
        z1s[r][col] = fmaxf(v, 0.f);
    }
    __syncthreads();

    // ---- layer 2: z2[2][256], 8-way k-split, rotated ------------------------
    {
        int cg = tid & 63;         // cols 4cg..4cg+3
        int ks = tid >> 6;         // k-slice 0..7, K=64 each
        int k0 = ks * 64;
        int roff2 = roff & 63;
        f32x4 a0 = {0.f, 0.f, 0.f, 0.f}, a1 = {0.f, 0.f, 0.f, 0.f};
        const float* wp = Wh2 + cg * 4;
#pragma unroll 4
        for (int kk = 0; kk < 64; kk++) {
            int k = k0 + ((kk + roff2) & 63);
            f32x4 wv = *(const f32x4*)(wp + (size_t)k * 256);
            float z0 = z1s[0][k], z1v = z1s[1][k];
            a0[0] = fmaf(z0, wv[0], a0[0]);  a1[0] = fmaf(z1v, wv[0], a1[0]);
            a0[1] = fmaf(z0, wv[1], a0[1]);  a1[1] = fmaf(z1v, wv[1], a1[1]);
            a0[2] = fmaf(z0, wv[2], a0[2]);  a1[2] = fmaf(z1v, wv[2], a1[2]);
            a0[3] = fmaf(z0, wv[3], a0[3]);  a1[3] = fmaf(z1v, wv[3], a1[3]);
        }
        *(f32x4*)&z2p[ks][0][cg * 4] = a0;
        *(f32x4*)&z2p[ks][1][cg * 4] = a1;
    }
    __syncthreads();
    {
        int r = tid >> 8, col = tid & 255;   // 512 threads = 2 x 256 exactly
        float v = bh2[col];
#pragma unroll
        for (int j = 0; j < 8; j++) v += z2p[j][r][col];
        z2s[r][col] = fmaxf(v, 0.f);
    }
    __syncthreads();

    // ---- layer 3: 2 batches x 9 cols x 16 k-slices --------------------------
    if (tid < 288) {
        int r = tid / 144, rem = tid - r * 144;
        int c = rem % 9, ks = rem / 9;     // K=16 each
        float a = 0.f;
#pragma unroll
        for (int k = 0; k < 16; k++)
            a = fmaf(z2s[r][ks * 16 + k], wh3s[(ks * 16 + k) * 9 + c], a);
        l3p[ks][r][c] = a;
    }
    __syncthreads();
    if (tid < 18) {
        int r = tid / 9, c = tid - r * 9;
        float a = bh3[c];
#pragma unroll
        for (int j = 0; j < 16; j++) a += l3p[j][r][c];
        raw[r][c] = a;
    }
    __syncthreads();

    if (tid < 2)
        svd_so3(&raw[tid][0], out + (size_t)(b0 + tid) * 9);
}

// ---------------------------------------------------------------------------
extern "C" void kernel_launch(void* const* d_in, const int* in_sizes, int n_in,
                              void* d_out, int out_size, void* d_ws, size_t ws_size,
                              hipStream_t stream)
{
    const float* x   = (const float*)d_in[0];
    const float* W1  = (const float*)d_in[1];
    const float* b1  = (const float*)d_in[2];
    const float* W2  = (const float*)d_in[3];
    const float* b2  = (const float*)d_in[4];
    const float* W3  = (const float*)d_in[5];
    const float* b3  = (const float*)d_in[6];
    const float* Wh1 = (const float*)d_in[7];
    const float* bh1 = (const float*)d_in[8];
    const float* Wh2 = (const float*)d_in[9];
    const float* bh2 = (const float*)d_in[10];
    const float* Wh3 = (const float*)d_in[11];
    const float* bh3 = (const float*)d_in[12];
    float* out = (float*)d_out;

    char* ws = (char*)d_ws;
    f16*   W2t = (f16*)ws;                  // 16 KB
    f16*   W3t = (f16*)(ws + 65536);        // 256 KB
    float* wpk = (float*)(ws + 524288);     // 1 KB
    float* g   = (float*)(ws + 1048576);    // 1 MB

    prep_weights<<<128, 256, 0, stream>>>(W1, b1, W2, W3, W2t, W3t, wpk);
    pointnet_fused<<<256, 512, 0, stream>>>(x, wpk, W2t, b2, W3t, b3, g);
    head_batched<<<128, 512, 0, stream>>>(g, Wh1, bh1, Wh2, bh2, Wh3, bh3, out);
}